// Round 1
// baseline (493.801 us; speedup 1.0000x reference)
//
#include <hip/hip_runtime.h>

// GridManifoldNetwork: fused multi-res hash-grid encode + MLP(15->64->1).
// N = 2,097,152 points, fp32 throughout.
//
// Levels: res = 16,32,64,128,256,512; F=2 features; T=2^19.
// Dense (res^3 <= T): levels 0..2. Hashed: levels 3..5, size = 2^19 exactly
// -> modulo becomes & 0x7FFFF.
// Offsets (entries): cumsum of [4096, 32768, 262144, 524288, 524288, 524288].

static __device__ __forceinline__ unsigned umin_(unsigned a, unsigned b) {
    return a < b ? a : b;
}

__global__ __launch_bounds__(256) void grid_mlp_kernel(
    const float* __restrict__ x,
    const float* __restrict__ grid,
    const float* __restrict__ W0,
    const float* __restrict__ b0,
    const float* __restrict__ W1,
    const float* __restrict__ b1,
    float* __restrict__ out, int N)
{
    // W0 transposed into LDS: sW0T[j][i] = W0[i*64+j], with b0[j] in slot i=15.
    __shared__ float sW0T[64 * 16];
    __shared__ float sW1[64];

    const int tid = threadIdx.x;
    for (int t = tid; t < 960; t += 256) {
        int j = t / 15;
        int i = t - j * 15;
        sW0T[j * 16 + i] = W0[i * 64 + j];
    }
    if (tid < 64) {
        sW0T[tid * 16 + 15] = b0[tid];
        sW1[tid] = W1[tid];
    }
    __syncthreads();

    const int gid = blockIdx.x * 256 + tid;
    if (gid >= N) return;

    const float px = x[3 * gid + 0];
    const float py = x[3 * gid + 1];
    const float pz = x[3 * gid + 2];
    const float xn0 = (px + 1.0f) * 0.5f;
    const float xn1 = (py + 1.0f) * 0.5f;
    const float xn2 = (pz + 1.0f) * 0.5f;

    float h[16];
    h[0] = px; h[1] = py; h[2] = pz;
    h[15] = 1.0f;   // bias slot

    const float2* gtab = (const float2*)grid;

    constexpr int      RES[6] = {16, 32, 64, 128, 256, 512};
    constexpr unsigned OFF[6] = {0u, 4096u, 36864u, 299008u, 823296u, 1347584u};
    constexpr unsigned P1 = 2654435761u, P2 = 805459861u;
    constexpr unsigned HMASK = (1u << 19) - 1u;

    #pragma unroll
    for (int l = 0; l < 6; ++l) {
        const float scale = (float)(RES[l] - 1);
        const float p0 = fmaf(xn0, scale, 0.5f);
        const float p1 = fmaf(xn1, scale, 0.5f);
        const float p2 = fmaf(xn2, scale, 0.5f);
        const float g0 = floorf(p0), g1 = floorf(p1), g2 = floorf(p2);
        const float f0 = p0 - g0, f1 = p1 - g1, f2 = p2 - g2;
        const unsigned i0 = (unsigned)g0, i1 = (unsigned)g1, i2 = (unsigned)g2;

        const float wx[2] = {1.0f - f0, f0};
        const float wy[2] = {1.0f - f1, f1};
        const float wz[2] = {1.0f - f2, f2};

        float a0 = 0.0f, a1 = 0.0f;

        if (l < 3) {  // dense: idx = cx + cy*res + cz*res^2, clamped
            const unsigned rm1 = (unsigned)(RES[l] - 1);
            const unsigned res = (unsigned)RES[l];
            const unsigned cx[2] = {umin_(i0, rm1), umin_(i0 + 1u, rm1)};
            const unsigned cy[2] = {umin_(i1, rm1) * res, umin_(i1 + 1u, rm1) * res};
            const unsigned cz[2] = {umin_(i2, rm1) * res * res,
                                    umin_(i2 + 1u, rm1) * res * res};
            #pragma unroll
            for (int corner = 0; corner < 8; ++corner) {
                const int bx = corner & 1, by = (corner >> 1) & 1, bz = (corner >> 2) & 1;
                const unsigned idx = cx[bx] + cy[by] + cz[bz];
                const float w = wx[bx] * wy[by] * wz[bz];
                const float2 v = gtab[OFF[l] + idx];
                a0 = fmaf(w, v.x, a0);
                a1 = fmaf(w, v.y, a1);
            }
        } else {      // hashed: idx = (cx*1 ^ cy*P1 ^ cz*P2) & (2^19-1)
            const unsigned hx[2] = {i0, i0 + 1u};
            const unsigned hy[2] = {i1 * P1, (i1 + 1u) * P1};
            const unsigned hz[2] = {i2 * P2, (i2 + 1u) * P2};
            #pragma unroll
            for (int corner = 0; corner < 8; ++corner) {
                const int bx = corner & 1, by = (corner >> 1) & 1, bz = (corner >> 2) & 1;
                const unsigned idx = (hx[bx] ^ hy[by] ^ hz[bz]) & HMASK;
                const float w = wx[bx] * wy[by] * wz[bz];
                const float2 v = gtab[OFF[l] + idx];
                a0 = fmaf(w, v.x, a0);
                a1 = fmaf(w, v.y, a1);
            }
        }
        h[3 + 2 * l] = a0;
        h[4 + 2 * l] = a1;
    }

    // MLP: out = relu(h @ W0 + b0) @ W1 + b1, bias folded via h[15]=1.
    float o = b1[0];
    #pragma unroll 8
    for (int j = 0; j < 64; ++j) {
        float s = 0.0f;
        #pragma unroll
        for (int i = 0; i < 16; ++i)
            s = fmaf(h[i], sW0T[j * 16 + i], s);   // uniform addr -> LDS broadcast
        s = fmaxf(s, 0.0f);
        o = fmaf(s, sW1[j], o);
    }
    out[gid] = o;
}

extern "C" void kernel_launch(void* const* d_in, const int* in_sizes, int n_in,
                              void* d_out, int out_size, void* d_ws, size_t ws_size,
                              hipStream_t stream) {
    const float* x    = (const float*)d_in[0];
    const float* grid = (const float*)d_in[1];
    const float* W0   = (const float*)d_in[2];
    const float* b0   = (const float*)d_in[3];
    const float* W1   = (const float*)d_in[4];
    const float* b1   = (const float*)d_in[5];
    float* out = (float*)d_out;

    const int N = in_sizes[0] / 3;
    const int blocks = (N + 255) / 256;
    grid_mlp_kernel<<<blocks, 256, 0, stream>>>(x, grid, W0, b0, W1, b1, out, N);
}

// Round 2
// 357.903 us; speedup vs baseline: 1.3797x; 1.3797x over previous
//
#include <hip/hip_runtime.h>

// GridManifoldNetwork, round 2: level-split multi-pass.
//
// R1 showed FETCH_SIZE=1.39GB (ideal ~50MB): random 8B gathers over a ~15MB
// working set thrash the 4MiB per-XCD L2. Fix: one dispatch per hashed level
// (each table = exactly 4MB = L2-resident, read-only so every XCD caches it),
// partial features staged in d_ws; final dispatch does dense levels
// (2.3MB total, L2-resident) + MLP. Streaming traffic (x, feat, out) uses
// non-temporal loads/stores to avoid evicting the resident table.
//
// Levels: res=16,32,64,128,256,512; F=2; T=2^19; levels 3..5 hashed with
// size 2^19 -> modulo is & 0x7FFFF.
// Entry offsets: 0, 4096, 36864, 299008, 823296, 1347584.

static __device__ __forceinline__ unsigned umin_(unsigned a, unsigned b) {
    return a < b ? a : b;
}

#define HP1 2654435761u
#define HP2 805459861u
#define HMASK ((1u << 19) - 1u)

// One hashed level: gather 8 corners from a single 4MB table, write float2.
__global__ __launch_bounds__(256) void hash_level_kernel(
    const float* __restrict__ x,
    const float2* __restrict__ tab,   // grid + level entry offset
    float2* __restrict__ feat,        // [N] partial features for this level
    float scale, int N)
{
    const int gid = blockIdx.x * 256 + threadIdx.x;
    if (gid >= N) return;

    const float px = __builtin_nontemporal_load(x + 3 * gid + 0);
    const float py = __builtin_nontemporal_load(x + 3 * gid + 1);
    const float pz = __builtin_nontemporal_load(x + 3 * gid + 2);

    const float p0 = fmaf((px + 1.0f) * 0.5f, scale, 0.5f);
    const float p1 = fmaf((py + 1.0f) * 0.5f, scale, 0.5f);
    const float p2 = fmaf((pz + 1.0f) * 0.5f, scale, 0.5f);
    const float g0 = floorf(p0), g1 = floorf(p1), g2 = floorf(p2);
    const float f0 = p0 - g0, f1 = p1 - g1, f2 = p2 - g2;
    const unsigned i0 = (unsigned)g0, i1 = (unsigned)g1, i2 = (unsigned)g2;

    const float wx[2] = {1.0f - f0, f0};
    const float wy[2] = {1.0f - f1, f1};
    const float wz[2] = {1.0f - f2, f2};
    const unsigned hx[2] = {i0, i0 + 1u};
    const unsigned hy[2] = {i1 * HP1, (i1 + 1u) * HP1};
    const unsigned hz[2] = {i2 * HP2, (i2 + 1u) * HP2};

    // Compute all 8 indices, issue all 8 loads, then accumulate.
    unsigned idx[8];
    float w[8];
    #pragma unroll
    for (int c = 0; c < 8; ++c) {
        const int bx = c & 1, by = (c >> 1) & 1, bz = (c >> 2) & 1;
        idx[c] = (hx[bx] ^ hy[by] ^ hz[bz]) & HMASK;
        w[c] = wx[bx] * wy[by] * wz[bz];
    }
    float2 v[8];
    #pragma unroll
    for (int c = 0; c < 8; ++c) v[c] = tab[idx[c]];

    float a0 = 0.0f, a1 = 0.0f;
    #pragma unroll
    for (int c = 0; c < 8; ++c) {
        a0 = fmaf(w[c], v[c].x, a0);
        a1 = fmaf(w[c], v[c].y, a1);
    }
    float* fp = (float*)(feat + gid);
    __builtin_nontemporal_store(a0, fp + 0);
    __builtin_nontemporal_store(a1, fp + 1);
}

// Dense levels 0..2 (tables total 2.3MB, L2-resident) + MLP(15->64->1).
__global__ __launch_bounds__(256) void dense_mlp_kernel(
    const float* __restrict__ x,
    const float* __restrict__ grid,
    const float2* __restrict__ feat,  // [3][N]: levels 3,4,5
    const float* __restrict__ W0,
    const float* __restrict__ b0,
    const float* __restrict__ W1,
    const float* __restrict__ b1,
    float* __restrict__ out, int N)
{
    __shared__ float sW0T[64 * 16];   // sW0T[j][i] = W0[i*64+j], b0 in i=15
    __shared__ float sW1[64];

    const int tid = threadIdx.x;
    for (int t = tid; t < 960; t += 256) {
        int j = t / 15;
        int i = t - j * 15;
        sW0T[j * 16 + i] = W0[i * 64 + j];
    }
    if (tid < 64) {
        sW0T[tid * 16 + 15] = b0[tid];
        sW1[tid] = W1[tid];
    }
    __syncthreads();

    const int gid = blockIdx.x * 256 + tid;
    if (gid >= N) return;

    const float px = __builtin_nontemporal_load(x + 3 * gid + 0);
    const float py = __builtin_nontemporal_load(x + 3 * gid + 1);
    const float pz = __builtin_nontemporal_load(x + 3 * gid + 2);
    const float xn0 = (px + 1.0f) * 0.5f;
    const float xn1 = (py + 1.0f) * 0.5f;
    const float xn2 = (pz + 1.0f) * 0.5f;

    float h[16];
    h[0] = px; h[1] = py; h[2] = pz;
    h[15] = 1.0f;   // bias slot

    const float2* gtab = (const float2*)grid;

    constexpr int      RES[3] = {16, 32, 64};
    constexpr unsigned OFF[3] = {0u, 4096u, 36864u};

    #pragma unroll
    for (int l = 0; l < 3; ++l) {
        const float scale = (float)(RES[l] - 1);
        const float p0 = fmaf(xn0, scale, 0.5f);
        const float p1 = fmaf(xn1, scale, 0.5f);
        const float p2 = fmaf(xn2, scale, 0.5f);
        const float g0 = floorf(p0), g1 = floorf(p1), g2 = floorf(p2);
        const float f0 = p0 - g0, f1 = p1 - g1, f2 = p2 - g2;
        const unsigned i0 = (unsigned)g0, i1 = (unsigned)g1, i2 = (unsigned)g2;

        const float wx[2] = {1.0f - f0, f0};
        const float wy[2] = {1.0f - f1, f1};
        const float wz[2] = {1.0f - f2, f2};

        const unsigned rm1 = (unsigned)(RES[l] - 1);
        const unsigned res = (unsigned)RES[l];
        const unsigned cx[2] = {umin_(i0, rm1), umin_(i0 + 1u, rm1)};
        const unsigned cy[2] = {umin_(i1, rm1) * res, umin_(i1 + 1u, rm1) * res};
        const unsigned cz[2] = {umin_(i2, rm1) * res * res,
                                umin_(i2 + 1u, rm1) * res * res};

        float a0 = 0.0f, a1 = 0.0f;
        #pragma unroll
        for (int c = 0; c < 8; ++c) {
            const int bx = c & 1, by = (c >> 1) & 1, bz = (c >> 2) & 1;
            const unsigned idx = cx[bx] + cy[by] + cz[bz];
            const float w = wx[bx] * wy[by] * wz[bz];
            const float2 v = gtab[OFF[l] + idx];
            a0 = fmaf(w, v.x, a0);
            a1 = fmaf(w, v.y, a1);
        }
        h[3 + 2 * l] = a0;
        h[4 + 2 * l] = a1;
    }

    // Hashed-level partial features from d_ws.
    #pragma unroll
    for (int l = 0; l < 3; ++l) {
        const float* fp = (const float*)(feat + (size_t)l * N + gid);
        h[9 + 2 * l]  = __builtin_nontemporal_load(fp + 0);
        h[10 + 2 * l] = __builtin_nontemporal_load(fp + 1);
    }

    // MLP: out = relu(h @ W0 + b0) @ W1 + b1, bias folded via h[15]=1.
    float o = b1[0];
    #pragma unroll 8
    for (int j = 0; j < 64; ++j) {
        float s = 0.0f;
        #pragma unroll
        for (int i = 0; i < 16; ++i)
            s = fmaf(h[i], sW0T[j * 16 + i], s);   // uniform addr -> LDS broadcast
        s = fmaxf(s, 0.0f);
        o = fmaf(s, sW1[j], o);
    }
    __builtin_nontemporal_store(o, out + gid);
}

extern "C" void kernel_launch(void* const* d_in, const int* in_sizes, int n_in,
                              void* d_out, int out_size, void* d_ws, size_t ws_size,
                              hipStream_t stream) {
    const float* x    = (const float*)d_in[0];
    const float* grid = (const float*)d_in[1];
    const float* W0   = (const float*)d_in[2];
    const float* b0   = (const float*)d_in[3];
    const float* W1   = (const float*)d_in[4];
    const float* b1   = (const float*)d_in[5];
    float* out = (float*)d_out;

    const int N = in_sizes[0] / 3;
    const int blocks = (N + 255) / 256;

    const float2* gtab = (const float2*)grid;
    float2* feat = (float2*)d_ws;               // [3][N] float2 = 48MB

    // Hashed levels 3,4,5: entry offsets 299008, 823296, 1347584.
    hash_level_kernel<<<blocks, 256, 0, stream>>>(x, gtab + 299008u,
                                                  feat + (size_t)0 * N, 127.0f, N);
    hash_level_kernel<<<blocks, 256, 0, stream>>>(x, gtab + 823296u,
                                                  feat + (size_t)1 * N, 255.0f, N);
    hash_level_kernel<<<blocks, 256, 0, stream>>>(x, gtab + 1347584u,
                                                  feat + (size_t)2 * N, 511.0f, N);
    dense_mlp_kernel<<<blocks, 256, 0, stream>>>(x, grid, feat, W0, b0, W1, b1,
                                                 out, N);
}